// Round 9
// baseline (95.620 us; speedup 1.0000x reference)
//
#include <hip/hip_runtime.h>

typedef int v4i __attribute__((ext_vector_type(4)));

// ---- weight workspace layout (int32 units) ----
#define W0i   0       // 9   int codes (8-bit, -128..127)
#define DW1i  9       // 27  int codes (4-bit)
#define PW1i  36      // 96  int codes
#define DW2i  132     // 288 int codes (legacy)
#define DW3i  420     // 576 int codes (legacy)
#define PW2p  996     // 512  packed i8x4 (legacy)
#define PW3p  1508    // 2048 packed (legacy)
#define WC1p  3556    // 8192 packed:  [o=0..255][k4=0..31]
#define WC2p  11748   // 640  packed:  [o=0..9][k4=0..63]
#define PW2Fb 12388   // 512  dwords: pw2 B-frags [nt(4)][lane(64)][dw(2)]
#define PW3Fb 12900   // 2048 dwords: pw3 B-frags [nt(8)*2+kh][lane(64)][dw(2)]
#define DW2pk 14948   // 144  dwords: dw2 pk16 pairs [cq(8)][t9(9)][e/o]
#define DW3pk 15092   // 288  dwords: dw3 pk16 pairs [cq(16)][t9(9)][e/o]
#define WTOT  15380

__device__ __forceinline__ int iclamp(int v, int lo, int hi) {
  return v < lo ? lo : (v > hi ? hi : v);
}
// round-half-even of a/4 and a/32 (exact jnp.round semantics, all-integer)
__device__ __forceinline__ int rne4(int a) {
  return (a + 1 + ((a >> 2) & 1)) >> 2;
}
__device__ __forceinline__ int rne32(int a) {
  return (a + 15 + ((a >> 5) & 1)) >> 5;
}

// LDS-only barrier: all inter-thread communication is via LDS; global
// accesses are read-only weights, so never drain vmcnt at barriers.
__device__ __forceinline__ void bar_lds() {
  asm volatile("s_waitcnt lgkmcnt(0)\n\ts_barrier" ::: "memory");
}
// in-wave LDS visibility (no s_barrier): drain LDS queue only
__device__ __forceinline__ void wait_lds() {
  asm volatile("s_waitcnt lgkmcnt(0)" ::: "memory");
}

__device__ __forceinline__ int dot4(int a, int b, int c) {
#if defined(__has_builtin) && __has_builtin(__builtin_amdgcn_sdot4)
  return __builtin_amdgcn_sdot4(a, b, c, false);
#else
  c += ((a << 24) >> 24) * ((b << 24) >> 24);
  c += ((a << 16) >> 24) * ((b << 16) >> 24);
  c += ((a <<  8) >> 24) * ((b <<  8) >> 24);
  c += (a >> 24) * (b >> 24);
  return c;
#endif
}

__device__ __forceinline__ int alignb(int hi, int lo, int sh) {
#if defined(__has_builtin) && __has_builtin(__builtin_amdgcn_alignbyte)
  return __builtin_amdgcn_alignbyte(hi, lo, sh);
#else
  return (int)(((((unsigned long long)(unsigned)hi) << 32) |
                (unsigned)lo) >> (8 * sh));
#endif
}

__device__ __forceinline__ int pack3(int a, int b, int c) {
  return (a & 0xff) | ((b & 0xff) << 8) | ((c & 0xff) << 16);
}

// ---- VOP3P packed-i16 helpers ----
__device__ __forceinline__ int pk_mad16(int a, int b, int c) {
  int d;
  asm("v_pk_mad_i16 %0, %1, %2, %3" : "=v"(d) : "v"(a), "v"(b), "v"(c));
  return d;
}
__device__ __forceinline__ int pk_add16(int a, int b) {
  int d;
  asm("v_pk_add_i16 %0, %1, %2" : "=v"(d) : "v"(a), "v"(b));
  return d;
}
__device__ __forceinline__ int pk_ashr16(int sh, int a) {
  int d;
  asm("v_pk_ashrrev_i16 %0, %1, %2" : "=v"(d) : "v"(sh), "v"(a));
  return d;
}
__device__ __forceinline__ int pk_max16(int a, int b) {
  int d;
  asm("v_pk_max_i16 %0, %1, %2" : "=v"(d) : "v"(a), "v"(b));
  return d;
}
__device__ __forceinline__ int pk_min16(int a, int b) {
  int d;
  asm("v_pk_min_i16 %0, %1, %2" : "=v"(d) : "v"(a), "v"(b));
  return d;
}
// packed rne(a/4) then clamp to [-8,7] per 16-bit lane (exact RNE)
__device__ __forceinline__ int rne4s_pk(int a) {
  const int sh = 0x00020002, one = 0x00010001;
  int t = pk_ashr16(sh, a);
  t &= one;
  t += one;
  int s4 = pk_add16(a, t);
  int r = pk_ashr16(sh, s4);
  r = pk_max16(r, (int)0xFFF8FFF8);
  r = pk_min16(r, 0x00070007);
  return r;
}

__device__ __forceinline__ int max4(v4i d) {
  int a = d[0] > d[1] ? d[0] : d[1];
  int b = d[2] > d[3] ? d[2] : d[3];
  return a > b ? a : b;
}

__global__ __launch_bounds__(256) void prep_weights(
    const float* __restrict__ w0,  const float* __restrict__ dw1,
    const float* __restrict__ pw1, const float* __restrict__ dw2,
    const float* __restrict__ pw2, const float* __restrict__ dw3,
    const float* __restrict__ pw3, const float* __restrict__ wc1,
    const float* __restrict__ wc2, int* __restrict__ ws) {
  int t = blockIdx.x * blockDim.x + threadIdx.x;
  if (t >= WTOT) return;
  if (t < PW2p) {
    float w; int lo = -8, hi = 7;
    if (t < DW1i)      { w = w0[t];        lo = -128; hi = 127; }
    else if (t < PW1i)   w = dw1[t - DW1i];
    else if (t < DW2i)   w = pw1[t - PW1i];
    else if (t < DW3i)   w = dw2[t - DW2i];
    else                 w = dw3[t - DW3i];
    ws[t] = iclamp((int)rintf(w * 4.f), lo, hi);
  } else if (t < PW2Fb) {
    const float* src;
    if (t < WC1p) {
      if (t < PW3p) src = pw2 + (t - PW2p) * 4;
      else          src = pw3 + (t - PW3p) * 4;
    } else {
      if (t < WC2p) src = wc1 + (t - WC1p) * 4;
      else          src = wc2 + (t - WC2p) * 4;
    }
    int p = 0;
#pragma unroll
    for (int b = 0; b < 4; b++) {
      int c = iclamp((int)rintf(src[b] * 4.f), -8, 7);
      p |= (c & 0xff) << (8 * b);
    }
    ws[t] = p;
  } else if (t < PW3Fb) {
    // pw2 MFMA B-fragment: B[k][n], n=nt*16+(lane&15), k=(lane>>4)*8+dw*4+b
    int i = t - PW2Fb;
    int nt = i >> 7, r = i & 127, lane = r >> 1, dw = r & 1;
    int n = nt * 16 + (lane & 15);
    int kb = (lane >> 4) * 8 + dw * 4;
    int p = 0;
#pragma unroll
    for (int b = 0; b < 4; b++) {
      int c = iclamp((int)rintf(pw2[n * 32 + kb + b] * 4.f), -8, 7);
      p |= (c & 0xff) << (8 * b);
    }
    ws[t] = p;
  } else if (t < DW2pk) {
    // pw3 MFMA B-fragment: k = kh*32 + (lane>>4)*8 + dw*4 + b
    int i = t - PW3Fb;
    int g = i >> 7, r = i & 127, lane = r >> 1, dw = r & 1;
    int nt = g >> 1, kh = g & 1;
    int n = nt * 16 + (lane & 15);
    int kb = kh * 32 + (lane >> 4) * 8 + dw * 4;
    int p = 0;
#pragma unroll
    for (int b = 0; b < 4; b++) {
      int c = iclamp((int)rintf(pw3[n * 64 + kb + b] * 4.f), -8, 7);
      p |= (c & 0xff) << (8 * b);
    }
    ws[t] = p;
  } else if (t < DW3pk) {
    int i = t - DW2pk;
    int cq = i / 18, r = i - cq * 18, t9 = r >> 1, par = r & 1;
    int wl = iclamp((int)rintf(dw2[(cq * 4 + par) * 9 + t9] * 4.f), -8, 7);
    int wh = iclamp((int)rintf(dw2[(cq * 4 + 2 + par) * 9 + t9] * 4.f), -8, 7);
    ws[t] = (wl & 0xFFFF) | (wh << 16);
  } else {
    int i = t - DW3pk;
    int cq = i / 18, r = i - cq * 18, t9 = r >> 1, par = r & 1;
    int wl = iclamp((int)rintf(dw3[(cq * 4 + par) * 9 + t9] * 4.f), -8, 7);
    int wh = iclamp((int)rintf(dw3[(cq * 4 + 2 + par) * 9 + t9] * 4.f), -8, 7);
    ws[t] = (wl & 0xFFFF) | (wh << 16);
  }
}

// 256 threads/block, 1024 blocks -> 4 blocks/CU, 16 waves/CU. 5 barriers.
// LDS ping-pong (read one buf, write the other — never both in a stage):
//  A0:  [c][256] dwords                       (stage0 -> M)    bufA
//  A1:  dword = y*149 + x*9 + cq   (16x16)    (M -> 2a)        bufB
//  Apw2: MFMA A, byte = m*40 + k; m = (qp^((qp>>3)&3))*4 + d   bufA
//  A2:  dword = py*137 + px*17 + oq (8x8)     (2b -> 3a)       bufB
//  Apw3: MFMA A, byte = pos*72 + k, k=ch (K=64)                bufA
//  fcin: bytes 0..127                          (3b -> fc1)     bufB
//  fc2in: bytes 0..255                         (fc1 -> fc2, wave0-only) bufA
__global__ __launch_bounds__(256, 4) void fused_net(
    const float* __restrict__ x,   // (1024,3,32,32)
    const int*   __restrict__ wq,
    float* __restrict__ out)       // (1024,10)
{
  const int img = blockIdx.x;
  const int tid = threadIdx.x;
  const int wv = tid >> 6, lane = tid & 63;
  const int lm = lane & 15, kg = lane >> 4;

  __shared__ __align__(16) int bufAi[2560];
  __shared__ __align__(16) int bufBi[2592];

  // ---- prefetch per-lane MFMA B-fragments (stay in flight across bar_lds) ----
  const int ntp = (wv & 1) * 2;              // stage 2b nt base
  const long bw0 = *(const long*)(wq + PW2Fb + (ntp * 64 + lane) * 2);
  const long bw1 = *(const long*)(wq + PW2Fb + ((ntp + 1) * 64 + lane) * 2);
  long b0v[2], b1v[2];
#pragma unroll
  for (int h = 0; h < 2; h++) {
    int nt = wv * 2 + h;                     // stage 3b nt
    b0v[h] = *(const long*)(wq + PW3Fb + (nt * 2 + 0) * 128 + lane * 2);
    b1v[h] = *(const long*)(wq + PW3Fb + (nt * 2 + 1) * 128 + lane * 2);
  }

  // ---- stage 0: input quant(8b) + 1x1 conv w0 + 4b quant -> A0 (bufA) ----
  {
    const float* xim = x + (size_t)img * 3072;
    const int p4 = tid * 4;
    float4 v0 = *(const float4*)(xim + p4);
    float4 v1 = *(const float4*)(xim + 1024 + p4);
    float4 v2 = *(const float4*)(xim + 2048 + p4);
    int w[9];
#pragma unroll
    for (int i = 0; i < 9; i++) w[i] = wq[W0i + i];
#define Q8(v) iclamp((int)rintf((v) * 16.f), -128, 127)
    int a0[4] = {Q8(v0.x), Q8(v0.y), Q8(v0.z), Q8(v0.w)};
    int a1[4] = {Q8(v1.x), Q8(v1.y), Q8(v1.z), Q8(v1.w)};
    int a2[4] = {Q8(v2.x), Q8(v2.y), Q8(v2.z), Q8(v2.w)};
#undef Q8
#pragma unroll
    for (int o = 0; o < 3; o++) {
      int pk = 0;
#pragma unroll
      for (int j = 0; j < 4; j++) {
        int s = a0[j] * w[o * 3] + a1[j] * w[o * 3 + 1] + a2[j] * w[o * 3 + 2];
        pk |= (iclamp(rne32(s), -8, 7) & 0xff) << (8 * j);
      }
      bufAi[o * 256 + tid] = pk;
    }
  }
  bar_lds();

  // ---- stage M (merged 1b+1c): one thread per pooled pos (py,px).
  // dw1 3x3 over own 2x2 window via dual-shifted dot4 weights, then
  // pw1 (3->32) + relu-q + pool2 + requant, A0(bufA) -> A1(bufB). ----
  {
    const int py = tid >> 4, px = tid & 15;
    int wr[3][3], wrh[3][3];
#pragma unroll
    for (int c = 0; c < 3; c++)
#pragma unroll
      for (int ky = 0; ky < 3; ky++) {
        int w = pack3(wq[DW1i + c * 9 + ky * 3],
                      wq[DW1i + c * 9 + ky * 3 + 1],
                      wq[DW1i + c * 9 + ky * 3 + 2]);
        wr[c][ky] = w;
        wrh[c][ky] = w << 8;
      }
    const int s = (px & 1) ? 1 : 3;
    const int D0 = (2 * px - 1) >> 2;        // -1 when px==0
    int V[3][4];
#pragma unroll
    for (int r = 0; r < 4; r++) {
      int rr = 2 * py - 1 + r;
      bool ok = (unsigned)rr < 32u;
#pragma unroll
      for (int c = 0; c < 3; c++) {
        int lo = 0, hi = 0;
        if (ok) {
          const int* ap = bufAi + c * 256 + rr * 8;
          if (px > 0)  lo = ap[D0];
          if (px < 15) hi = ap[D0 + 1];
        }
        V[c][r] = alignb(hi, lo, s);
      }
    }
    int a[4];
#pragma unroll
    for (int dy = 0; dy < 2; dy++) {
      int r01[3];
#pragma unroll
      for (int c = 0; c < 3; c++) {
        int acc0 = 0, acc1 = 0;
#pragma unroll
        for (int ky = 0; ky < 3; ky++) {
          acc0 = dot4(V[c][dy + ky], wr[c][ky], acc0);   // dx = 0
          acc1 = dot4(V[c][dy + ky], wrh[c][ky], acc1);  // dx = 1
        }
        int p = (int)__builtin_amdgcn_perm((unsigned)acc1, (unsigned)acc0,
                                           0x05040100u);
        r01[c] = rne4s_pk(p);                // codes -8..7 per 16-bit lane
      }
      unsigned t0 = __builtin_amdgcn_perm((unsigned)r01[1], (unsigned)r01[0],
                                          0x0C0C0400u);
      a[2 * dy] = (int)__builtin_amdgcn_perm((unsigned)r01[2], t0, 0x0C040100u);
      unsigned t1 = __builtin_amdgcn_perm((unsigned)r01[1], (unsigned)r01[0],
                                          0x0C0C0602u);
      a[2 * dy + 1] =
          (int)__builtin_amdgcn_perm((unsigned)r01[2], t1, 0x0C060100u);
    }
#pragma unroll
    for (int it = 0; it < 8; it++) {
      int pk = 0;
#pragma unroll
      for (int j = 0; j < 4; j++) {
        int o = it * 4 + j;
        int wpk = pack3(wq[PW1i + o * 3], wq[PW1i + o * 3 + 1],
                        wq[PW1i + o * 3 + 2]);
        int m0 = dot4(a[0], wpk, 0), m1 = dot4(a[1], wpk, 0);
        int m2 = dot4(a[2], wpk, 0), m3 = dot4(a[3], wpk, 0);
        int mx = max(max(m0, m1), max(m2, m3));
        pk |= iclamp(rne4(mx), 0, 7) << (8 * j);
      }
      bufBi[py * 149 + px * 9 + it] = pk;
    }
  }
  bar_lds();

  // ---- stage 2a: dw 3x3, 32ch 16x16, pk_mad_i16, single pass (8-px strip).
  // A1(bufB) -> Apw2(bufA), MFMA-A layout with XOR pool-window swizzle. ----
  {
    const int cq = tid >> 5;                 // 0..7
    const int rem = tid & 31;
    const int y = rem >> 1, xh = rem & 1, x0 = xh * 8;
    int we[9], wo[9];
    {
      const int2* wp = (const int2*)(wq + DW2pk + cq * 18);
#pragma unroll
      for (int t9 = 0; t9 < 9; t9++) { int2 v = wp[t9]; we[t9] = v.x; wo[t9] = v.y; }
    }
    int acce[8] = {}, acco[8] = {};
#pragma unroll
    for (int ky = 0; ky < 3; ky++) {
      int yy = y + ky - 1;
      if (yy < 0 || yy > 15) continue;
      int rb = yy * 149 + cq;
      int rd[10];
      rd[0] = (x0 > 0) ? bufBi[rb + (x0 - 1) * 9] : 0;
#pragma unroll
      for (int k = 1; k < 9; k++) rd[k] = bufBi[rb + (x0 - 1 + k) * 9];
      rd[9] = (x0 < 8) ? bufBi[rb + (x0 + 8) * 9] : 0;
      int ee[10], eo[10];
#pragma unroll
      for (int k = 0; k < 10; k++) {
        ee[k] = rd[k] & 0x000F000F;
        eo[k] = (rd[k] >> 8) & 0x000F000F;
      }
#pragma unroll
      for (int j = 0; j < 8; j++)
#pragma unroll
        for (int kx = 0; kx < 3; kx++) {
          acce[j] = pk_mad16(ee[j + kx], we[ky * 3 + kx], acce[j]);
          acco[j] = pk_mad16(eo[j + kx], wo[ky * 3 + kx], acco[j]);
        }
    }
    const int py = y >> 1, dy = y & 1;
#pragma unroll
    for (int j = 0; j < 8; j++) {
      int xx = x0 + j;
      int qp = py * 8 + (xx >> 1);
      int q = qp ^ (py & 3);                 // XOR swizzle (involution)
      int m = q * 4 + dy * 2 + (xx & 1);
      int re = rne4s_pk(acce[j]);
      int ro = rne4s_pk(acco[j]);
      bufAi[m * 10 + cq] = (re & 0x00FF00FF) | ((ro & 0x00FF00FF) << 8);
    }
  }
  bar_lds();

  // ---- stage 2b: pw2 via MFMA i32_16x16x32_i8, fused relu+pool2 -> A2(bufB) ----
  {
    const int mtb = (wv >> 1) * 8;
    const signed char* Ab = (const signed char*)bufAi;
    signed char* A2c = (signed char*)bufBi;
    const int n0 = ntp * 16 + lm, n1 = (ntp + 1) * 16 + lm;
#pragma unroll 4
    for (int mt = mtb; mt < mtb + 8; mt++) {
      int m = mt * 16 + lm;
      long av = *(const long*)(Ab + m * 40 + kg * 8);
      v4i d0 = __builtin_amdgcn_mfma_i32_16x16x32_i8(av, bw0, (v4i){0, 0, 0, 0},
                                                     0, 0, 0);
      v4i d1 = __builtin_amdgcn_mfma_i32_16x16x32_i8(av, bw1, (v4i){0, 0, 0, 0},
                                                     0, 0, 0);
      int q = mt * 4 + kg;
      int qp = q ^ ((q >> 3) & 3);           // un-swizzle
      int py = qp >> 3, px = qp & 7;
      int bb = (py * 137 + px * 17) * 4;
      A2c[bb + n0] = (signed char)iclamp(rne4(max4(d0)), 0, 7);
      A2c[bb + n1] = (signed char)iclamp(rne4(max4(d1)), 0, 7);
    }
  }
  bar_lds();

  // ---- stage 3a: dw 3x3, 64ch 8x8, pk_mad_i16 (strip of 4) A2(bufB)->Apw3(bufA) ----
  {
    int cq2 = tid >> 4;                      // 0..15
    int s = tid & 15;
    int y = s >> 1, x0 = (s & 1) << 2;
    int we[9], wo[9];
    {
      const int2* wp = (const int2*)(wq + DW3pk + cq2 * 18);
#pragma unroll
      for (int t9 = 0; t9 < 9; t9++) { int2 v = wp[t9]; we[t9] = v.x; wo[t9] = v.y; }
    }
    int acce[4] = {}, acco[4] = {};
#pragma unroll
    for (int ky = 0; ky < 3; ky++) {
      int yy = y + ky - 1;
      if (yy < 0 || yy > 7) continue;
      int rb = yy * 137 + cq2;
      int rd[6];
      rd[0] = (x0 == 4) ? bufBi[rb + (x0 - 1) * 17] : 0;
      rd[1] = bufBi[rb + x0 * 17];
      rd[2] = bufBi[rb + (x0 + 1) * 17];
      rd[3] = bufBi[rb + (x0 + 2) * 17];
      rd[4] = bufBi[rb + (x0 + 3) * 17];
      rd[5] = (x0 == 0) ? bufBi[rb + (x0 + 4) * 17] : 0;
      int ee[6], eo[6];
#pragma unroll
      for (int k = 0; k < 6; k++) {
        ee[k] = rd[k] & 0x000F000F;
        eo[k] = (rd[k] >> 8) & 0x000F000F;
      }
#pragma unroll
      for (int j = 0; j < 4; j++)
#pragma unroll
        for (int kx = 0; kx < 3; kx++) {
          acce[j] = pk_mad16(ee[j + kx], we[ky * 3 + kx], acce[j]);
          acco[j] = pk_mad16(eo[j + kx], wo[ky * 3 + kx], acco[j]);
        }
    }
#pragma unroll
    for (int j = 0; j < 4; j++) {
      int re = rne4s_pk(acce[j]);
      int ro = rne4s_pk(acco[j]);
      bufAi[(y * 8 + x0 + j) * 18 + cq2] =
          (re & 0x00FF00FF) | ((ro & 0x00FF00FF) << 8);
    }
  }
  bar_lds();

  // ---- stage 3b: pw3 via MFMA (K=64 as 2x K=32) + global max pool -> fcin(bufB) ----
  {
    const signed char* Ab = (const signed char*)bufAi;
    signed char* fcin = (signed char*)bufBi;
    int mx[2] = {-1000000, -1000000};
#pragma unroll
    for (int mt = 0; mt < 4; mt++) {
      int m = mt * 16 + lm;
      long a0 = *(const long*)(Ab + m * 72 + kg * 8);
      long a1 = *(const long*)(Ab + m * 72 + 32 + kg * 8);
#pragma unroll
      for (int h = 0; h < 2; h++) {
        v4i d = __builtin_amdgcn_mfma_i32_16x16x32_i8(a0, b0v[h],
                                                      (v4i){0, 0, 0, 0}, 0, 0, 0);
        d = __builtin_amdgcn_mfma_i32_16x16x32_i8(a1, b1v[h], d, 0, 0, 0);
        int t4 = max4(d);
        mx[h] = mx[h] > t4 ? mx[h] : t4;
      }
    }
#pragma unroll
    for (int h = 0; h < 2; h++) {
      int red = max(mx[h], __shfl_xor(mx[h], 16));
      red = max(red, __shfl_xor(red, 32));
      if (lane < 16)
        fcin[(wv * 2 + h) * 16 + lm] = (signed char)iclamp(rne4(red), 0, 7);
    }
  }
  bar_lds();

  // ---- fc tail: wave 0 only (in-wave LDS visibility, no more barriers).
  // Waves 1-3 retire, freeing their SIMD slots for other resident blocks. ----
  if (wv != 0) return;

  // fc1: 128 -> 256. Lane computes outputs {oi*64+lane}, oi=0..3,
  // two output columns in flight to overlap the L2 weight-load latency.
  {
    const int4* mp = (const int4*)bufBi;     // fcin: 8 int4
    int4 av[8];
#pragma unroll
    for (int rI = 0; rI < 8; rI++) av[rI] = mp[rI];
    signed char* fc2in = (signed char*)bufAi;
#pragma unroll
    for (int oi = 0; oi < 4; oi += 2) {
      int o0 = oi * 64 + lane, o1 = (oi + 1) * 64 + lane;
      const int4* w0p = (const int4*)(wq + WC1p + o0 * 32);
      const int4* w1p = (const int4*)(wq + WC1p + o1 * 32);
      int acc0 = 0, acc1 = 0;
#pragma unroll
      for (int rI = 0; rI < 8; rI++) {
        int4 a = av[rI];
        int4 w0v = w0p[rI], w1v = w1p[rI];
        acc0 = dot4(a.x, w0v.x, acc0); acc0 = dot4(a.y, w0v.y, acc0);
        acc0 = dot4(a.z, w0v.z, acc0); acc0 = dot4(a.w, w0v.w, acc0);
        acc1 = dot4(a.x, w1v.x, acc1); acc1 = dot4(a.y, w1v.y, acc1);
        acc1 = dot4(a.z, w1v.z, acc1); acc1 = dot4(a.w, w1v.w, acc1);
      }
      fc2in[o0] = (signed char)iclamp(rne4(acc0), 0, 7);
      fc2in[o1] = (signed char)iclamp(rne4(acc1), 0, 7);
    }
  }
  wait_lds();                                // same-wave ds_write -> ds_read

  // fc2: 256 -> 10, lanes 0..39 (4 lanes per class) + shfl reduce
  if (lane < 40) {
    int k = lane >> 2, j = lane & 3;
    const int4* wp = (const int4*)(wq + WC2p + k * 64 + j * 16);
    const int4* ap = (const int4*)bufAi;
    int acc = 0;
#pragma unroll
    for (int r = 0; r < 4; r++) {
      int4 a = ap[j * 4 + r]; int4 w = wp[r];
      acc = dot4(a.x, w.x, acc); acc = dot4(a.y, w.y, acc);
      acc = dot4(a.z, w.z, acc); acc = dot4(a.w, w.w, acc);
    }
    acc += __shfl_xor(acc, 1);
    acc += __shfl_xor(acc, 2);
    if (j == 0) {
      // value = acc*0.125; fq_signed(v, 2^-4, 8b): round(v*16) = 2*acc exactly
      int code = iclamp(2 * acc, -128, 127);
      out[(size_t)img * 10 + k] = (float)code * 0.0625f;
    }
  }
}

extern "C" void kernel_launch(void* const* d_in, const int* in_sizes, int n_in,
                              void* d_out, int out_size, void* d_ws, size_t ws_size,
                              hipStream_t stream) {
  const float* x   = (const float*)d_in[0];
  const float* w0  = (const float*)d_in[1];
  const float* dw1 = (const float*)d_in[2];
  const float* pw1 = (const float*)d_in[3];
  const float* dw2 = (const float*)d_in[4];
  const float* pw2 = (const float*)d_in[5];
  const float* dw3 = (const float*)d_in[6];
  const float* pw3 = (const float*)d_in[7];
  const float* wc1 = (const float*)d_in[8];
  const float* wc2 = (const float*)d_in[9];
  int*   wsq = (int*)d_ws;     // 15380 ints = 61.5 KB (L2-resident)
  float* out = (float*)d_out;  // (1024,10,1,1) fp32

  prep_weights<<<(WTOT + 255) / 256, 256, 0, stream>>>(
      w0, dw1, pw1, dw2, pw2, dw3, pw3, wc1, wc2, wsq);
  fused_net<<<1024, 256, 0, stream>>>(x, wsq, out);
}

// Round 10
// 93.410 us; speedup vs baseline: 1.0237x; 1.0237x over previous
//
#include <hip/hip_runtime.h>

typedef int v4i __attribute__((ext_vector_type(4)));

// ---- weight workspace layout (int32 units) ----
#define W0i   0       // 9   int codes (8-bit, -128..127)
#define DW1i  9       // 27  int codes (4-bit)
#define PW1i  36      // 96  int codes
#define DW2i  132     // legacy region start (unused by fused_net)
#define WC1p  3556    // 8192 packed:  [o=0..255][k4=0..31]
#define WC2p  11748   // 640  packed:  [o=0..9][k4=0..63]
#define PW2Fb 12388   // 512  dwords: pw2 B-frags [nt(4)][lane(64)][dw(2)]
#define PW3Fb 12900   // 2048 dwords: pw3 B-frags [nt(8)*2+kh][lane(64)][dw(2)]
#define DW2pk 14948   // 144  dwords: dw2 pk16 pairs [cq(8)][t9(9)][e/o]
#define DW3pk 15092   // 288  dwords: dw3 pk16 pairs [cq(16)][t9(9)][e/o]
#define WTOT  15380

__device__ __forceinline__ int iclamp(int v, int lo, int hi) {
  return v < lo ? lo : (v > hi ? hi : v);
}
// round-half-even of a/4 and a/32 (exact jnp.round semantics, all-integer)
__device__ __forceinline__ int rne4(int a) {
  return (a + 1 + ((a >> 2) & 1)) >> 2;
}
__device__ __forceinline__ int rne32(int a) {
  return (a + 15 + ((a >> 5) & 1)) >> 5;
}

// LDS-only barrier: all inter-thread communication is via LDS; global
// accesses are read-only weights, so never drain vmcnt at barriers.
__device__ __forceinline__ void bar_lds() {
  asm volatile("s_waitcnt lgkmcnt(0)\n\ts_barrier" ::: "memory");
}

__device__ __forceinline__ int dot4(int a, int b, int c) {
#if defined(__has_builtin) && __has_builtin(__builtin_amdgcn_sdot4)
  return __builtin_amdgcn_sdot4(a, b, c, false);
#else
  c += ((a << 24) >> 24) * ((b << 24) >> 24);
  c += ((a << 16) >> 24) * ((b << 16) >> 24);
  c += ((a <<  8) >> 24) * ((b <<  8) >> 24);
  c += (a >> 24) * (b >> 24);
  return c;
#endif
}

__device__ __forceinline__ int alignb(int hi, int lo, int sh) {
#if defined(__has_builtin) && __has_builtin(__builtin_amdgcn_alignbyte)
  return __builtin_amdgcn_alignbyte(hi, lo, sh);
#else
  return (int)(((((unsigned long long)(unsigned)hi) << 32) |
                (unsigned)lo) >> (8 * sh));
#endif
}

__device__ __forceinline__ int pack3(int a, int b, int c) {
  return (a & 0xff) | ((b & 0xff) << 8) | ((c & 0xff) << 16);
}

// ---- VOP3P packed-i16 helpers ----
__device__ __forceinline__ int pk_mad16(int a, int b, int c) {
  int d;
  asm("v_pk_mad_i16 %0, %1, %2, %3" : "=v"(d) : "v"(a), "v"(b), "v"(c));
  return d;
}
__device__ __forceinline__ int pk_add16(int a, int b) {
  int d;
  asm("v_pk_add_i16 %0, %1, %2" : "=v"(d) : "v"(a), "v"(b));
  return d;
}
__device__ __forceinline__ int pk_ashr16(int sh, int a) {
  int d;
  asm("v_pk_ashrrev_i16 %0, %1, %2" : "=v"(d) : "v"(sh), "v"(a));
  return d;
}
__device__ __forceinline__ int pk_max16(int a, int b) {
  int d;
  asm("v_pk_max_i16 %0, %1, %2" : "=v"(d) : "v"(a), "v"(b));
  return d;
}
__device__ __forceinline__ int pk_min16(int a, int b) {
  int d;
  asm("v_pk_min_i16 %0, %1, %2" : "=v"(d) : "v"(a), "v"(b));
  return d;
}
// packed rne(a/4) then clamp to [-8,7] per 16-bit lane (exact RNE)
__device__ __forceinline__ int rne4s_pk(int a) {
  const int sh = 0x00020002, one = 0x00010001;
  int t = pk_ashr16(sh, a);
  t &= one;
  t += one;
  int s4 = pk_add16(a, t);
  int r = pk_ashr16(sh, s4);
  r = pk_max16(r, (int)0xFFF8FFF8);
  r = pk_min16(r, 0x00070007);
  return r;
}

__device__ __forceinline__ int max4(v4i d) {
  int a = d[0] > d[1] ? d[0] : d[1];
  int b = d[2] > d[3] ? d[2] : d[3];
  return a > b ? a : b;
}

__global__ __launch_bounds__(256) void prep_weights(
    const float* __restrict__ w0,  const float* __restrict__ dw1,
    const float* __restrict__ pw1, const float* __restrict__ dw2,
    const float* __restrict__ pw2, const float* __restrict__ dw3,
    const float* __restrict__ pw3, const float* __restrict__ wc1,
    const float* __restrict__ wc2, int* __restrict__ ws) {
  int t = blockIdx.x * blockDim.x + threadIdx.x;
  if (t >= WTOT) return;
  if (t >= DW2i && t < WC1p) return;   // legacy region, never read
  if (t < DW2i) {
    float w; int lo = -8, hi = 7;
    if (t < DW1i)      { w = w0[t];        lo = -128; hi = 127; }
    else if (t < PW1i)   w = dw1[t - DW1i];
    else                 w = pw1[t - PW1i];
    ws[t] = iclamp((int)rintf(w * 4.f), lo, hi);
  } else if (t < PW2Fb) {
    const float* src = (t < WC2p) ? wc1 + (t - WC1p) * 4
                                  : wc2 + (t - WC2p) * 4;
    int p = 0;
#pragma unroll
    for (int b = 0; b < 4; b++) {
      int c = iclamp((int)rintf(src[b] * 4.f), -8, 7);
      p |= (c & 0xff) << (8 * b);
    }
    ws[t] = p;
  } else if (t < PW3Fb) {
    // pw2 MFMA B-fragment: B[k][n], n=nt*16+(lane&15), k=(lane>>4)*8+dw*4+b
    int i = t - PW2Fb;
    int nt = i >> 7, r = i & 127, lane = r >> 1, dw = r & 1;
    int n = nt * 16 + (lane & 15);
    int kb = (lane >> 4) * 8 + dw * 4;
    int p = 0;
#pragma unroll
    for (int b = 0; b < 4; b++) {
      int c = iclamp((int)rintf(pw2[n * 32 + kb + b] * 4.f), -8, 7);
      p |= (c & 0xff) << (8 * b);
    }
    ws[t] = p;
  } else if (t < DW2pk) {
    // pw3 MFMA B-fragment: k = kh*32 + (lane>>4)*8 + dw*4 + b
    int i = t - PW3Fb;
    int g = i >> 7, r = i & 127, lane = r >> 1, dw = r & 1;
    int nt = g >> 1, kh = g & 1;
    int n = nt * 16 + (lane & 15);
    int kb = kh * 32 + (lane >> 4) * 8 + dw * 4;
    int p = 0;
#pragma unroll
    for (int b = 0; b < 4; b++) {
      int c = iclamp((int)rintf(pw3[n * 64 + kb + b] * 4.f), -8, 7);
      p |= (c & 0xff) << (8 * b);
    }
    ws[t] = p;
  } else if (t < DW3pk) {
    int i = t - DW2pk;
    int cq = i / 18, r = i - cq * 18, t9 = r >> 1, par = r & 1;
    int wl = iclamp((int)rintf(dw2[(cq * 4 + par) * 9 + t9] * 4.f), -8, 7);
    int wh = iclamp((int)rintf(dw2[(cq * 4 + 2 + par) * 9 + t9] * 4.f), -8, 7);
    ws[t] = (wl & 0xFFFF) | (wh << 16);
  } else {
    int i = t - DW3pk;
    int cq = i / 18, r = i - cq * 18, t9 = r >> 1, par = r & 1;
    int wl = iclamp((int)rintf(dw3[(cq * 4 + par) * 9 + t9] * 4.f), -8, 7);
    int wh = iclamp((int)rintf(dw3[(cq * 4 + 2 + par) * 9 + t9] * 4.f), -8, 7);
    ws[t] = (wl & 0xFFFF) | (wh << 16);
  }
}

// 256 threads/block, 1024 blocks -> 4 blocks/CU, 16 waves/CU. 7 barriers.
// LDS ping-pong (read one buf, write the other — never both in a stage):
//  A0:  [c][256] dwords                       (stage0 -> M)    bufA
//  A1:  dword = y*149 + x*9 + cq   (16x16)    (M -> 2a)        bufB
//  Apw2: MFMA A, byte = m*40 + k; m = (qp^((qp>>3)&3))*4 + d   bufA
//  A2:  dword = py*137 + px*17 + oq (8x8)     (2b -> 3a)       bufB
//  Apw3: MFMA A, byte = pos*72 + k, k=ch (K=64)                bufA
//  fcin: bytes 0..127                          (3b -> fc1)     bufB
//  fc2in: bytes 0..255                         (fc1 -> fc2)    bufA
__global__ __launch_bounds__(256, 4) void fused_net(
    const float* __restrict__ x,   // (1024,3,32,32)
    const int*   __restrict__ wq,
    float* __restrict__ out)       // (1024,10)
{
  const int img = blockIdx.x;
  const int tid = threadIdx.x;
  const int wv = tid >> 6, lane = tid & 63;
  const int lm = lane & 15, kg = lane >> 4;

  __shared__ __align__(16) int bufAi[2560];
  __shared__ __align__(16) int bufBi[2592];

  // ---- prefetch per-lane MFMA B-fragments (stay in flight across bar_lds) ----
  const int ntp = (wv & 1) * 2;              // stage 2b nt base
  const long bw0 = *(const long*)(wq + PW2Fb + (ntp * 64 + lane) * 2);
  const long bw1 = *(const long*)(wq + PW2Fb + ((ntp + 1) * 64 + lane) * 2);
  long b0v[2], b1v[2];
#pragma unroll
  for (int h = 0; h < 2; h++) {
    int nt = wv * 2 + h;                     // stage 3b nt
    b0v[h] = *(const long*)(wq + PW3Fb + (nt * 2 + 0) * 128 + lane * 2);
    b1v[h] = *(const long*)(wq + PW3Fb + (nt * 2 + 1) * 128 + lane * 2);
  }

  // ---- stage 0: input quant(8b) + 1x1 conv w0 + 4b quant -> A0 (bufA) ----
  {
    const float* xim = x + (size_t)img * 3072;
    const int p4 = tid * 4;
    float4 v0 = *(const float4*)(xim + p4);
    float4 v1 = *(const float4*)(xim + 1024 + p4);
    float4 v2 = *(const float4*)(xim + 2048 + p4);
    int w[9];
#pragma unroll
    for (int i = 0; i < 9; i++) w[i] = wq[W0i + i];
#define Q8(v) iclamp((int)rintf((v) * 16.f), -128, 127)
    int a0[4] = {Q8(v0.x), Q8(v0.y), Q8(v0.z), Q8(v0.w)};
    int a1[4] = {Q8(v1.x), Q8(v1.y), Q8(v1.z), Q8(v1.w)};
    int a2[4] = {Q8(v2.x), Q8(v2.y), Q8(v2.z), Q8(v2.w)};
#undef Q8
#pragma unroll
    for (int o = 0; o < 3; o++) {
      int pk = 0;
#pragma unroll
      for (int j = 0; j < 4; j++) {
        int s = a0[j] * w[o * 3] + a1[j] * w[o * 3 + 1] + a2[j] * w[o * 3 + 2];
        pk |= (iclamp(rne32(s), -8, 7) & 0xff) << (8 * j);
      }
      bufAi[o * 256 + tid] = pk;
    }
  }
  bar_lds();

  // ---- stage M (merged 1b+1c): one thread per pooled pos (py,px).
  // dw1 3x3 over own 2x2 window via dual-shifted dot4 weights, then
  // pw1 (3->32) + relu-q + pool2 + requant, A0(bufA) -> A1(bufB). ----
  {
    const int py = tid >> 4, px = tid & 15;
    int wr[3][3], wrh[3][3];
#pragma unroll
    for (int c = 0; c < 3; c++)
#pragma unroll
      for (int ky = 0; ky < 3; ky++) {
        int w = pack3(wq[DW1i + c * 9 + ky * 3],
                      wq[DW1i + c * 9 + ky * 3 + 1],
                      wq[DW1i + c * 9 + ky * 3 + 2]);
        wr[c][ky] = w;
        wrh[c][ky] = w << 8;
      }
    const int s = (px & 1) ? 1 : 3;
    const int D0 = (2 * px - 1) >> 2;        // -1 when px==0
    int V[3][4];
#pragma unroll
    for (int r = 0; r < 4; r++) {
      int rr = 2 * py - 1 + r;
      bool ok = (unsigned)rr < 32u;
#pragma unroll
      for (int c = 0; c < 3; c++) {
        int lo = 0, hi = 0;
        if (ok) {
          const int* ap = bufAi + c * 256 + rr * 8;
          if (px > 0)  lo = ap[D0];
          if (px < 15) hi = ap[D0 + 1];
        }
        V[c][r] = alignb(hi, lo, s);
      }
    }
    int a[4];
#pragma unroll
    for (int dy = 0; dy < 2; dy++) {
      int r01[3];
#pragma unroll
      for (int c = 0; c < 3; c++) {
        int acc0 = 0, acc1 = 0;
#pragma unroll
        for (int ky = 0; ky < 3; ky++) {
          acc0 = dot4(V[c][dy + ky], wr[c][ky], acc0);   // dx = 0
          acc1 = dot4(V[c][dy + ky], wrh[c][ky], acc1);  // dx = 1
        }
        int p = (int)__builtin_amdgcn_perm((unsigned)acc1, (unsigned)acc0,
                                           0x05040100u);
        r01[c] = rne4s_pk(p);                // codes -8..7 per 16-bit lane
      }
      unsigned t0 = __builtin_amdgcn_perm((unsigned)r01[1], (unsigned)r01[0],
                                          0x0C0C0400u);
      a[2 * dy] = (int)__builtin_amdgcn_perm((unsigned)r01[2], t0, 0x0C040100u);
      unsigned t1 = __builtin_amdgcn_perm((unsigned)r01[1], (unsigned)r01[0],
                                          0x0C0C0602u);
      a[2 * dy + 1] =
          (int)__builtin_amdgcn_perm((unsigned)r01[2], t1, 0x0C060100u);
    }
#pragma unroll
    for (int it = 0; it < 8; it++) {
      int pk = 0;
#pragma unroll
      for (int j = 0; j < 4; j++) {
        int o = it * 4 + j;
        int wpk = pack3(wq[PW1i + o * 3], wq[PW1i + o * 3 + 1],
                        wq[PW1i + o * 3 + 2]);
        int m0 = dot4(a[0], wpk, 0), m1 = dot4(a[1], wpk, 0);
        int m2 = dot4(a[2], wpk, 0), m3 = dot4(a[3], wpk, 0);
        int mx = max(max(m0, m1), max(m2, m3));
        pk |= iclamp(rne4(mx), 0, 7) << (8 * j);
      }
      bufBi[py * 149 + px * 9 + it] = pk;
    }
  }
  bar_lds();

  // ---- stage 2a: dw 3x3, 32ch 16x16, pk_mad_i16, single pass (8-px strip).
  // A1(bufB) -> Apw2(bufA), MFMA-A layout with XOR pool-window swizzle. ----
  {
    const int cq = tid >> 5;                 // 0..7
    const int rem = tid & 31;
    const int y = rem >> 1, xh = rem & 1, x0 = xh * 8;
    int we[9], wo[9];
    {
      const int2* wp = (const int2*)(wq + DW2pk + cq * 18);
#pragma unroll
      for (int t9 = 0; t9 < 9; t9++) { int2 v = wp[t9]; we[t9] = v.x; wo[t9] = v.y; }
    }
    int acce[8] = {}, acco[8] = {};
#pragma unroll
    for (int ky = 0; ky < 3; ky++) {
      int yy = y + ky - 1;
      if (yy < 0 || yy > 15) continue;
      int rb = yy * 149 + cq;
      int rd[10];
      rd[0] = (x0 > 0) ? bufBi[rb + (x0 - 1) * 9] : 0;
#pragma unroll
      for (int k = 1; k < 9; k++) rd[k] = bufBi[rb + (x0 - 1 + k) * 9];
      rd[9] = (x0 < 8) ? bufBi[rb + (x0 + 8) * 9] : 0;
      int ee[10], eo[10];
#pragma unroll
      for (int k = 0; k < 10; k++) {
        ee[k] = rd[k] & 0x000F000F;
        eo[k] = (rd[k] >> 8) & 0x000F000F;
      }
#pragma unroll
      for (int j = 0; j < 8; j++)
#pragma unroll
        for (int kx = 0; kx < 3; kx++) {
          acce[j] = pk_mad16(ee[j + kx], we[ky * 3 + kx], acce[j]);
          acco[j] = pk_mad16(eo[j + kx], wo[ky * 3 + kx], acco[j]);
        }
    }
    const int py = y >> 1, dy = y & 1;
#pragma unroll
    for (int j = 0; j < 8; j++) {
      int xx = x0 + j;
      int qp = py * 8 + (xx >> 1);
      int q = qp ^ (py & 3);                 // XOR swizzle (involution)
      int m = q * 4 + dy * 2 + (xx & 1);
      int re = rne4s_pk(acce[j]);
      int ro = rne4s_pk(acco[j]);
      bufAi[m * 10 + cq] = (re & 0x00FF00FF) | ((ro & 0x00FF00FF) << 8);
    }
  }
  // prefetch fc weights NOW: VMEM stays in flight across the next THREE
  // bar_lds boundaries (they never drain vmcnt); first use is in fc1/fc2.
  int4 wfc[8];
  {
    const int4* wp = (const int4*)(wq + WC1p + tid * 32);
#pragma unroll
    for (int rI = 0; rI < 8; rI++) wfc[rI] = wp[rI];
  }
  int4 wf2a = {0, 0, 0, 0}, wf2b = {0, 0, 0, 0};
  if (tid < 40) {
    int k = tid >> 2, j = tid & 3;
    const int4* wp = (const int4*)(wq + WC2p + k * 64 + j * 16);
    wf2a = wp[0]; wf2b = wp[1];
  }
  bar_lds();

  // ---- stage 2b: pw2 via MFMA i32_16x16x32_i8, fused relu+pool2 -> A2(bufB) ----
  {
    const int mtb = (wv >> 1) * 8;
    const signed char* Ab = (const signed char*)bufAi;
    signed char* A2c = (signed char*)bufBi;
    const int n0 = ntp * 16 + lm, n1 = (ntp + 1) * 16 + lm;
#pragma unroll 4
    for (int mt = mtb; mt < mtb + 8; mt++) {
      int m = mt * 16 + lm;
      long av = *(const long*)(Ab + m * 40 + kg * 8);
      v4i d0 = __builtin_amdgcn_mfma_i32_16x16x32_i8(av, bw0, (v4i){0, 0, 0, 0},
                                                     0, 0, 0);
      v4i d1 = __builtin_amdgcn_mfma_i32_16x16x32_i8(av, bw1, (v4i){0, 0, 0, 0},
                                                     0, 0, 0);
      int q = mt * 4 + kg;
      int qp = q ^ ((q >> 3) & 3);           // un-swizzle
      int py = qp >> 3, px = qp & 7;
      int bb = (py * 137 + px * 17) * 4;
      A2c[bb + n0] = (signed char)iclamp(rne4(max4(d0)), 0, 7);
      A2c[bb + n1] = (signed char)iclamp(rne4(max4(d1)), 0, 7);
    }
  }
  bar_lds();

  // ---- stage 3a: dw 3x3, 64ch 8x8, pk_mad_i16 (strip of 4) A2(bufB)->Apw3(bufA) ----
  {
    int cq2 = tid >> 4;                      // 0..15
    int s = tid & 15;
    int y = s >> 1, x0 = (s & 1) << 2;
    int we[9], wo[9];
    {
      const int2* wp = (const int2*)(wq + DW3pk + cq2 * 18);
#pragma unroll
      for (int t9 = 0; t9 < 9; t9++) { int2 v = wp[t9]; we[t9] = v.x; wo[t9] = v.y; }
    }
    int acce[4] = {}, acco[4] = {};
#pragma unroll
    for (int ky = 0; ky < 3; ky++) {
      int yy = y + ky - 1;
      if (yy < 0 || yy > 7) continue;
      int rb = yy * 137 + cq2;
      int rd[6];
      rd[0] = (x0 == 4) ? bufBi[rb + (x0 - 1) * 17] : 0;
      rd[1] = bufBi[rb + x0 * 17];
      rd[2] = bufBi[rb + (x0 + 1) * 17];
      rd[3] = bufBi[rb + (x0 + 2) * 17];
      rd[4] = bufBi[rb + (x0 + 3) * 17];
      rd[5] = (x0 == 0) ? bufBi[rb + (x0 + 4) * 17] : 0;
      int ee[6], eo[6];
#pragma unroll
      for (int k = 0; k < 6; k++) {
        ee[k] = rd[k] & 0x000F000F;
        eo[k] = (rd[k] >> 8) & 0x000F000F;
      }
#pragma unroll
      for (int j = 0; j < 4; j++)
#pragma unroll
        for (int kx = 0; kx < 3; kx++) {
          acce[j] = pk_mad16(ee[j + kx], we[ky * 3 + kx], acce[j]);
          acco[j] = pk_mad16(eo[j + kx], wo[ky * 3 + kx], acco[j]);
        }
    }
#pragma unroll
    for (int j = 0; j < 4; j++) {
      int re = rne4s_pk(acce[j]);
      int ro = rne4s_pk(acco[j]);
      bufAi[(y * 8 + x0 + j) * 18 + cq2] =
          (re & 0x00FF00FF) | ((ro & 0x00FF00FF) << 8);
    }
  }
  bar_lds();

  // ---- stage 3b: pw3 via MFMA (K=64 as 2x K=32) + global max pool -> fcin(bufB) ----
  {
    const signed char* Ab = (const signed char*)bufAi;
    signed char* fcin = (signed char*)bufBi;
    int mx[2] = {-1000000, -1000000};
#pragma unroll
    for (int mt = 0; mt < 4; mt++) {
      int m = mt * 16 + lm;
      long a0 = *(const long*)(Ab + m * 72 + kg * 8);
      long a1 = *(const long*)(Ab + m * 72 + 32 + kg * 8);
#pragma unroll
      for (int h = 0; h < 2; h++) {
        v4i d = __builtin_amdgcn_mfma_i32_16x16x32_i8(a0, b0v[h],
                                                      (v4i){0, 0, 0, 0}, 0, 0, 0);
        d = __builtin_amdgcn_mfma_i32_16x16x32_i8(a1, b1v[h], d, 0, 0, 0);
        int t4 = max4(d);
        mx[h] = mx[h] > t4 ? mx[h] : t4;
      }
    }
#pragma unroll
    for (int h = 0; h < 2; h++) {
      int red = max(mx[h], __shfl_xor(mx[h], 16));
      red = max(red, __shfl_xor(red, 32));
      if (lane < 16)
        fcin[(wv * 2 + h) * 16 + lm] = (signed char)iclamp(rne4(red), 0, 7);
    }
  }
  bar_lds();

  // ---- fc1: 128 -> 256 (sdot4, prefetched weights) fcin(bufB) -> fc2in(bufA) ----
  {
    const int4* mp = (const int4*)bufBi;
    int acc = 0;
#pragma unroll
    for (int rI = 0; rI < 8; rI++) {
      int4 a = mp[rI]; int4 w = wfc[rI];
      acc = dot4(a.x, w.x, acc); acc = dot4(a.y, w.y, acc);
      acc = dot4(a.z, w.z, acc); acc = dot4(a.w, w.w, acc);
    }
    ((signed char*)bufAi)[tid] = (signed char)iclamp(rne4(acc), 0, 7);
  }
  bar_lds();

  // ---- fc2: 256 -> 10, single-wave shfl reduction (prefetched weights) ----
  if (tid < 40) {
    int j = tid & 3;
    const int4* ap = (const int4*)bufAi;
    int4 a0 = ap[j * 4], a1 = ap[j * 4 + 1], a2 = ap[j * 4 + 2],
         a3 = ap[j * 4 + 3];
    int acc = dot4(a0.x, wf2a.x, 0);
    acc = dot4(a0.y, wf2a.y, acc); acc = dot4(a0.z, wf2a.z, acc);
    acc = dot4(a0.w, wf2a.w, acc);
    acc = dot4(a1.x, wf2b.x, acc); acc = dot4(a1.y, wf2b.y, acc);
    acc = dot4(a1.z, wf2b.z, acc); acc = dot4(a1.w, wf2b.w, acc);
    // second half: weights rows 2,3 of this (k,j) slice
    const int4* wp = (const int4*)(wq + WC2p + (tid >> 2) * 64 + j * 16);
    int4 w2 = wp[2], w3 = wp[3];
    acc = dot4(a2.x, w2.x, acc); acc = dot4(a2.y, w2.y, acc);
    acc = dot4(a2.z, w2.z, acc); acc = dot4(a2.w, w2.w, acc);
    acc = dot4(a3.x, w3.x, acc); acc = dot4(a3.y, w3.y, acc);
    acc = dot4(a3.z, w3.z, acc); acc = dot4(a3.w, w3.w, acc);
    acc += __shfl_xor(acc, 1);
    acc += __shfl_xor(acc, 2);
    if (j == 0) {
      // value = acc*0.125; fq_signed(v, 2^-4, 8b): round(v*16) = 2*acc exactly
      int code = iclamp(2 * acc, -128, 127);
      out[(size_t)img * 10 + (tid >> 2)] = (float)code * 0.0625f;
    }
  }
}

extern "C" void kernel_launch(void* const* d_in, const int* in_sizes, int n_in,
                              void* d_out, int out_size, void* d_ws, size_t ws_size,
                              hipStream_t stream) {
  const float* x   = (const float*)d_in[0];
  const float* w0  = (const float*)d_in[1];
  const float* dw1 = (const float*)d_in[2];
  const float* pw1 = (const float*)d_in[3];
  const float* dw2 = (const float*)d_in[4];
  const float* pw2 = (const float*)d_in[5];
  const float* dw3 = (const float*)d_in[6];
  const float* pw3 = (const float*)d_in[7];
  const float* wc1 = (const float*)d_in[8];
  const float* wc2 = (const float*)d_in[9];
  int*   wsq = (int*)d_ws;     // 15380 ints = 61.5 KB (L2-resident)
  float* out = (float*)d_out;  // (1024,10,1,1) fp32

  prep_weights<<<(WTOT + 255) / 256, 256, 0, stream>>>(
      w0, dw1, pw1, dw2, pw2, dw3, pw3, wc1, wc2, wsq);
  fused_net<<<1024, 256, 0, stream>>>(x, wsq, out);
}

// Round 11
// 92.945 us; speedup vs baseline: 1.0288x; 1.0050x over previous
//
#include <hip/hip_runtime.h>

typedef int v4i __attribute__((ext_vector_type(4)));

// ---- weight workspace layout (int32 units) ----
#define W0i   0       // 9   int codes (8-bit, -128..127)
#define DW1i  9       // 27  int codes (4-bit)
#define PW1i  36      // 96  int codes
#define DW2i  132     // legacy region start (unused by fused_net)
#define WC1p  3556    // 8192 packed:  [o=0..255][k4=0..31]
#define WC2p  11748   // 640  packed:  [o=0..9][k4=0..63]
#define PW2Fb 12388   // 512  dwords: pw2 B-frags [nt(4)][lane(64)][dw(2)]
#define PW3Fb 12900   // 2048 dwords: pw3 B-frags [nt(8)*2+kh][lane(64)][dw(2)]
#define DW2pk 14948   // 144  dwords: dw2 pk16 pairs [cq(8)][t9(9)][e/o]
#define DW3pk 15092   // 288  dwords: dw3 pk16 pairs [cq(16)][t9(9)][e/o]
#define WTOT  15380

__device__ __forceinline__ int iclamp(int v, int lo, int hi) {
  return v < lo ? lo : (v > hi ? hi : v);
}
// round-half-even of a/4 and a/32 (exact jnp.round semantics, all-integer)
__device__ __forceinline__ int rne4(int a) {
  return (a + 1 + ((a >> 2) & 1)) >> 2;
}
__device__ __forceinline__ int rne32(int a) {
  return (a + 15 + ((a >> 5) & 1)) >> 5;
}

// LDS-only barrier: all inter-thread communication is via LDS; global
// accesses are read-only weights, so never drain vmcnt at barriers.
__device__ __forceinline__ void bar_lds() {
  asm volatile("s_waitcnt lgkmcnt(0)\n\ts_barrier" ::: "memory");
}

__device__ __forceinline__ int dot4(int a, int b, int c) {
#if defined(__has_builtin) && __has_builtin(__builtin_amdgcn_sdot4)
  return __builtin_amdgcn_sdot4(a, b, c, false);
#else
  c += ((a << 24) >> 24) * ((b << 24) >> 24);
  c += ((a << 16) >> 24) * ((b << 16) >> 24);
  c += ((a <<  8) >> 24) * ((b <<  8) >> 24);
  c += (a >> 24) * (b >> 24);
  return c;
#endif
}

__device__ __forceinline__ int alignb(int hi, int lo, int sh) {
#if defined(__has_builtin) && __has_builtin(__builtin_amdgcn_alignbyte)
  return __builtin_amdgcn_alignbyte(hi, lo, sh);
#else
  return (int)(((((unsigned long long)(unsigned)hi) << 32) |
                (unsigned)lo) >> (8 * sh));
#endif
}

__device__ __forceinline__ int pack3(int a, int b, int c) {
  return (a & 0xff) | ((b & 0xff) << 8) | ((c & 0xff) << 16);
}

// ---- VOP3P packed-i16 helpers ----
__device__ __forceinline__ int pk_mad16(int a, int b, int c) {
  int d;
  asm("v_pk_mad_i16 %0, %1, %2, %3" : "=v"(d) : "v"(a), "v"(b), "v"(c));
  return d;
}
__device__ __forceinline__ int pk_add16(int a, int b) {
  int d;
  asm("v_pk_add_i16 %0, %1, %2" : "=v"(d) : "v"(a), "v"(b));
  return d;
}
__device__ __forceinline__ int pk_ashr16(int sh, int a) {
  int d;
  asm("v_pk_ashrrev_i16 %0, %1, %2" : "=v"(d) : "v"(sh), "v"(a));
  return d;
}
__device__ __forceinline__ int pk_max16(int a, int b) {
  int d;
  asm("v_pk_max_i16 %0, %1, %2" : "=v"(d) : "v"(a), "v"(b));
  return d;
}
__device__ __forceinline__ int pk_min16(int a, int b) {
  int d;
  asm("v_pk_min_i16 %0, %1, %2" : "=v"(d) : "v"(a), "v"(b));
  return d;
}
// packed rne(a/4) then clamp to [-8,7] per 16-bit lane (exact RNE)
__device__ __forceinline__ int rne4s_pk(int a) {
  const int sh = 0x00020002, one = 0x00010001;
  int t = pk_ashr16(sh, a);
  t &= one;
  t += one;
  int s4 = pk_add16(a, t);
  int r = pk_ashr16(sh, s4);
  r = pk_max16(r, (int)0xFFF8FFF8);
  r = pk_min16(r, 0x00070007);
  return r;
}

__device__ __forceinline__ int max4(v4i d) {
  int a = d[0] > d[1] ? d[0] : d[1];
  int b = d[2] > d[3] ? d[2] : d[3];
  return a > b ? a : b;
}

__global__ __launch_bounds__(256) void prep_weights(
    const float* __restrict__ w0,  const float* __restrict__ dw1,
    const float* __restrict__ pw1, const float* __restrict__ dw2,
    const float* __restrict__ pw2, const float* __restrict__ dw3,
    const float* __restrict__ pw3, const float* __restrict__ wc1,
    const float* __restrict__ wc2, int* __restrict__ ws) {
  int t = blockIdx.x * blockDim.x + threadIdx.x;
  if (t >= WTOT) return;
  if (t >= DW2i && t < WC1p) return;   // legacy region, never read
  if (t < DW2i) {
    float w; int lo = -8, hi = 7;
    if (t < DW1i)      { w = w0[t];        lo = -128; hi = 127; }
    else if (t < PW1i)   w = dw1[t - DW1i];
    else                 w = pw1[t - PW1i];
    ws[t] = iclamp((int)rintf(w * 4.f), lo, hi);
  } else if (t < PW2Fb) {
    const float* src = (t < WC2p) ? wc1 + (t - WC1p) * 4
                                  : wc2 + (t - WC2p) * 4;
    int p = 0;
#pragma unroll
    for (int b = 0; b < 4; b++) {
      int c = iclamp((int)rintf(src[b] * 4.f), -8, 7);
      p |= (c & 0xff) << (8 * b);
    }
    ws[t] = p;
  } else if (t < PW3Fb) {
    // pw2 MFMA B-fragment: B[k][n], n=nt*16+(lane&15), k=(lane>>4)*8+dw*4+b
    int i = t - PW2Fb;
    int nt = i >> 7, r = i & 127, lane = r >> 1, dw = r & 1;
    int n = nt * 16 + (lane & 15);
    int kb = (lane >> 4) * 8 + dw * 4;
    int p = 0;
#pragma unroll
    for (int b = 0; b < 4; b++) {
      int c = iclamp((int)rintf(pw2[n * 32 + kb + b] * 4.f), -8, 7);
      p |= (c & 0xff) << (8 * b);
    }
    ws[t] = p;
  } else if (t < DW2pk) {
    // pw3 MFMA B-fragment: k = kh*32 + (lane>>4)*8 + dw*4 + b
    int i = t - PW3Fb;
    int g = i >> 7, r = i & 127, lane = r >> 1, dw = r & 1;
    int nt = g >> 1, kh = g & 1;
    int n = nt * 16 + (lane & 15);
    int kb = kh * 32 + (lane >> 4) * 8 + dw * 4;
    int p = 0;
#pragma unroll
    for (int b = 0; b < 4; b++) {
      int c = iclamp((int)rintf(pw3[n * 64 + kb + b] * 4.f), -8, 7);
      p |= (c & 0xff) << (8 * b);
    }
    ws[t] = p;
  } else if (t < DW3pk) {
    int i = t - DW2pk;
    int cq = i / 18, r = i - cq * 18, t9 = r >> 1, par = r & 1;
    int wl = iclamp((int)rintf(dw2[(cq * 4 + par) * 9 + t9] * 4.f), -8, 7);
    int wh = iclamp((int)rintf(dw2[(cq * 4 + 2 + par) * 9 + t9] * 4.f), -8, 7);
    ws[t] = (wl & 0xFFFF) | (wh << 16);
  } else {
    int i = t - DW3pk;
    int cq = i / 18, r = i - cq * 18, t9 = r >> 1, par = r & 1;
    int wl = iclamp((int)rintf(dw3[(cq * 4 + par) * 9 + t9] * 4.f), -8, 7);
    int wh = iclamp((int)rintf(dw3[(cq * 4 + 2 + par) * 9 + t9] * 4.f), -8, 7);
    ws[t] = (wl & 0xFFFF) | (wh << 16);
  }
}

// 256 threads/block, 1024 blocks -> 4 blocks/CU, 16 waves/CU. 7 barriers.
// LDS ping-pong (read one buf, write the other — never both in a stage):
//  A0:  [c][256] dwords                       (stage0 -> M)    bufA
//  A1:  dword = y*149 + x*9 + cq   (16x16)    (M -> 2a)        bufB
//  Apw2: MFMA A, byte = m*40 + k; m = (qp^((qp>>3)&3))*4 + d   bufA
//  A2:  dword = py*137 + px*17 + oq (8x8)     (2b -> 3a)       bufB
//  Apw3: MFMA A, byte = pos*72 + k, k=ch (K=64)                bufA
//  fcin: bytes 0..127                          (3b -> fc1)     bufB
//  fc2in: bytes 0..255                         (fc1 -> fc2)    bufA
__global__ __launch_bounds__(256, 4) void fused_net(
    const float* __restrict__ x,   // (1024,3,32,32)
    const int*   __restrict__ wq,
    float* __restrict__ out)       // (1024,10)
{
  const int img = blockIdx.x;
  const int tid = threadIdx.x;
  const int wv = tid >> 6, lane = tid & 63;
  const int lm = lane & 15, kg = lane >> 4;

  __shared__ __align__(16) int bufAi[2560];
  __shared__ __align__(16) int bufBi[2592];

  // ---- prefetch per-lane MFMA B-fragments (stay in flight across bar_lds) ----
  const int ntp = (wv & 1) * 2;              // stage 2b nt base
  const long bw0 = *(const long*)(wq + PW2Fb + (ntp * 64 + lane) * 2);
  const long bw1 = *(const long*)(wq + PW2Fb + ((ntp + 1) * 64 + lane) * 2);
  long b0v[2], b1v[2];
#pragma unroll
  for (int h = 0; h < 2; h++) {
    int nt = wv * 2 + h;                     // stage 3b nt
    b0v[h] = *(const long*)(wq + PW3Fb + (nt * 2 + 0) * 128 + lane * 2);
    b1v[h] = *(const long*)(wq + PW3Fb + (nt * 2 + 1) * 128 + lane * 2);
  }

  // ---- stage 0: input quant(8b) + 1x1 conv w0 + 4b quant -> A0 (bufA) ----
  {
    const float* xim = x + (size_t)img * 3072;
    const int p4 = tid * 4;
    float4 v0 = *(const float4*)(xim + p4);
    float4 v1 = *(const float4*)(xim + 1024 + p4);
    float4 v2 = *(const float4*)(xim + 2048 + p4);
    int w[9];
#pragma unroll
    for (int i = 0; i < 9; i++) w[i] = wq[W0i + i];
#define Q8(v) iclamp((int)rintf((v) * 16.f), -128, 127)
    int a0[4] = {Q8(v0.x), Q8(v0.y), Q8(v0.z), Q8(v0.w)};
    int a1[4] = {Q8(v1.x), Q8(v1.y), Q8(v1.z), Q8(v1.w)};
    int a2[4] = {Q8(v2.x), Q8(v2.y), Q8(v2.z), Q8(v2.w)};
#undef Q8
#pragma unroll
    for (int o = 0; o < 3; o++) {
      int pk = 0;
#pragma unroll
      for (int j = 0; j < 4; j++) {
        int s = a0[j] * w[o * 3] + a1[j] * w[o * 3 + 1] + a2[j] * w[o * 3 + 2];
        pk |= (iclamp(rne32(s), -8, 7) & 0xff) << (8 * j);
      }
      bufAi[o * 256 + tid] = pk;
    }
  }
  bar_lds();

  // ---- stage M (merged 1b+1c): one thread per pooled pos (py,px).
  // dw1 3x3 over own 2x2 window via dual-shifted dot4 weights, then
  // pw1 (3->32) + relu-q + pool2 + requant, A0(bufA) -> A1(bufB). ----
  {
    const int py = tid >> 4, px = tid & 15;
    int wr[3][3], wrh[3][3];
#pragma unroll
    for (int c = 0; c < 3; c++)
#pragma unroll
      for (int ky = 0; ky < 3; ky++) {
        int w = pack3(wq[DW1i + c * 9 + ky * 3],
                      wq[DW1i + c * 9 + ky * 3 + 1],
                      wq[DW1i + c * 9 + ky * 3 + 2]);
        wr[c][ky] = w;
        wrh[c][ky] = w << 8;
      }
    const int s = (px & 1) ? 1 : 3;
    const int D0 = (2 * px - 1) >> 2;        // -1 when px==0
    int V[3][4];
#pragma unroll
    for (int r = 0; r < 4; r++) {
      int rr = 2 * py - 1 + r;
      bool ok = (unsigned)rr < 32u;
#pragma unroll
      for (int c = 0; c < 3; c++) {
        int lo = 0, hi = 0;
        if (ok) {
          const int* ap = bufAi + c * 256 + rr * 8;
          if (px > 0)  lo = ap[D0];
          if (px < 15) hi = ap[D0 + 1];
        }
        V[c][r] = alignb(hi, lo, s);
      }
    }
    int a[4];
#pragma unroll
    for (int dy = 0; dy < 2; dy++) {
      int r01[3];
#pragma unroll
      for (int c = 0; c < 3; c++) {
        int acc0 = 0, acc1 = 0;
#pragma unroll
        for (int ky = 0; ky < 3; ky++) {
          acc0 = dot4(V[c][dy + ky], wr[c][ky], acc0);   // dx = 0
          acc1 = dot4(V[c][dy + ky], wrh[c][ky], acc1);  // dx = 1
        }
        int p = (int)__builtin_amdgcn_perm((unsigned)acc1, (unsigned)acc0,
                                           0x05040100u);
        r01[c] = rne4s_pk(p);                // codes -8..7 per 16-bit lane
      }
      unsigned t0 = __builtin_amdgcn_perm((unsigned)r01[1], (unsigned)r01[0],
                                          0x0C0C0400u);
      a[2 * dy] = (int)__builtin_amdgcn_perm((unsigned)r01[2], t0, 0x0C040100u);
      unsigned t1 = __builtin_amdgcn_perm((unsigned)r01[1], (unsigned)r01[0],
                                          0x0C0C0602u);
      a[2 * dy + 1] =
          (int)__builtin_amdgcn_perm((unsigned)r01[2], t1, 0x0C060100u);
    }
#pragma unroll
    for (int it = 0; it < 8; it++) {
      int pk = 0;
#pragma unroll
      for (int j = 0; j < 4; j++) {
        int o = it * 4 + j;
        int wpk = pack3(wq[PW1i + o * 3], wq[PW1i + o * 3 + 1],
                        wq[PW1i + o * 3 + 2]);
        int m0 = dot4(a[0], wpk, 0), m1 = dot4(a[1], wpk, 0);
        int m2 = dot4(a[2], wpk, 0), m3 = dot4(a[3], wpk, 0);
        int mx = max(max(m0, m1), max(m2, m3));
        pk |= iclamp(rne4(mx), 0, 7) << (8 * j);
      }
      bufBi[py * 149 + px * 9 + it] = pk;
    }
  }
  bar_lds();

  // ---- stage 2a: dw 3x3, 32ch 16x16, pk_mad_i16, single pass (8-px strip).
  // A1(bufB) -> Apw2(bufA), MFMA-A layout with XOR pool-window swizzle. ----
  {
    const int cq = tid >> 5;                 // 0..7
    const int rem = tid & 31;
    const int y = rem >> 1, xh = rem & 1, x0 = xh * 8;
    int we[9], wo[9];
    {
      const int2* wp = (const int2*)(wq + DW2pk + cq * 18);
#pragma unroll
      for (int t9 = 0; t9 < 9; t9++) { int2 v = wp[t9]; we[t9] = v.x; wo[t9] = v.y; }
    }
    int acce[8] = {}, acco[8] = {};
#pragma unroll
    for (int ky = 0; ky < 3; ky++) {
      int yy = y + ky - 1;
      if (yy < 0 || yy > 15) continue;
      int rb = yy * 149 + cq;
      int rd[10];
      rd[0] = (x0 > 0) ? bufBi[rb + (x0 - 1) * 9] : 0;
#pragma unroll
      for (int k = 1; k < 9; k++) rd[k] = bufBi[rb + (x0 - 1 + k) * 9];
      rd[9] = (x0 < 8) ? bufBi[rb + (x0 + 8) * 9] : 0;
      int ee[10], eo[10];
#pragma unroll
      for (int k = 0; k < 10; k++) {
        ee[k] = rd[k] & 0x000F000F;
        eo[k] = (rd[k] >> 8) & 0x000F000F;
      }
#pragma unroll
      for (int j = 0; j < 8; j++)
#pragma unroll
        for (int kx = 0; kx < 3; kx++) {
          acce[j] = pk_mad16(ee[j + kx], we[ky * 3 + kx], acce[j]);
          acco[j] = pk_mad16(eo[j + kx], wo[ky * 3 + kx], acco[j]);
        }
    }
    const int py = y >> 1, dy = y & 1;
#pragma unroll
    for (int j = 0; j < 8; j++) {
      int xx = x0 + j;
      int qp = py * 8 + (xx >> 1);
      int q = qp ^ (py & 3);                 // XOR swizzle (involution)
      int m = q * 4 + dy * 2 + (xx & 1);
      int re = rne4s_pk(acce[j]);
      int ro = rne4s_pk(acco[j]);
      bufAi[m * 10 + cq] = (re & 0x00FF00FF) | ((ro & 0x00FF00FF) << 8);
    }
  }
  bar_lds();

  // ---- stage 2b: pw2 via MFMA i32_16x16x32_i8, fused relu+pool2 -> A2(bufB) ----
  {
    const int mtb = (wv >> 1) * 8;
    const signed char* Ab = (const signed char*)bufAi;
    signed char* A2c = (signed char*)bufBi;
    const int n0 = ntp * 16 + lm, n1 = (ntp + 1) * 16 + lm;
#pragma unroll 4
    for (int mt = mtb; mt < mtb + 8; mt++) {
      int m = mt * 16 + lm;
      long av = *(const long*)(Ab + m * 40 + kg * 8);
      v4i d0 = __builtin_amdgcn_mfma_i32_16x16x32_i8(av, bw0, (v4i){0, 0, 0, 0},
                                                     0, 0, 0);
      v4i d1 = __builtin_amdgcn_mfma_i32_16x16x32_i8(av, bw1, (v4i){0, 0, 0, 0},
                                                     0, 0, 0);
      int q = mt * 4 + kg;
      int qp = q ^ ((q >> 3) & 3);           // un-swizzle
      int py = qp >> 3, px = qp & 7;
      int bb = (py * 137 + px * 17) * 4;
      A2c[bb + n0] = (signed char)iclamp(rne4(max4(d0)), 0, 7);
      A2c[bb + n1] = (signed char)iclamp(rne4(max4(d1)), 0, 7);
    }
  }
  bar_lds();

  // ---- stage 3a: dw 3x3, 64ch 8x8, pk_mad_i16 (strip of 4) A2(bufB)->Apw3(bufA) ----
  {
    int cq2 = tid >> 4;                      // 0..15
    int s = tid & 15;
    int y = s >> 1, x0 = (s & 1) << 2;
    int we[9], wo[9];
    {
      const int2* wp = (const int2*)(wq + DW3pk + cq2 * 18);
#pragma unroll
      for (int t9 = 0; t9 < 9; t9++) { int2 v = wp[t9]; we[t9] = v.x; wo[t9] = v.y; }
    }
    int acce[4] = {}, acco[4] = {};
#pragma unroll
    for (int ky = 0; ky < 3; ky++) {
      int yy = y + ky - 1;
      if (yy < 0 || yy > 7) continue;
      int rb = yy * 137 + cq2;
      int rd[6];
      rd[0] = (x0 == 4) ? bufBi[rb + (x0 - 1) * 17] : 0;
      rd[1] = bufBi[rb + x0 * 17];
      rd[2] = bufBi[rb + (x0 + 1) * 17];
      rd[3] = bufBi[rb + (x0 + 2) * 17];
      rd[4] = bufBi[rb + (x0 + 3) * 17];
      rd[5] = (x0 == 0) ? bufBi[rb + (x0 + 4) * 17] : 0;
      int ee[6], eo[6];
#pragma unroll
      for (int k = 0; k < 6; k++) {
        ee[k] = rd[k] & 0x000F000F;
        eo[k] = (rd[k] >> 8) & 0x000F000F;
      }
#pragma unroll
      for (int j = 0; j < 4; j++)
#pragma unroll
        for (int kx = 0; kx < 3; kx++) {
          acce[j] = pk_mad16(ee[j + kx], we[ky * 3 + kx], acce[j]);
          acco[j] = pk_mad16(eo[j + kx], wo[ky * 3 + kx], acco[j]);
        }
    }
#pragma unroll
    for (int j = 0; j < 4; j++) {
      int re = rne4s_pk(acce[j]);
      int ro = rne4s_pk(acco[j]);
      bufAi[(y * 8 + x0 + j) * 18 + cq2] =
          (re & 0x00FF00FF) | ((ro & 0x00FF00FF) << 8);
    }
  }
  // prefetch fc1 weights now: VMEM stays in flight across the next two
  // bar_lds boundaries (they never drain vmcnt); first use is in fc1.
  int4 wfc[8];
  {
    const int4* wp = (const int4*)(wq + WC1p + tid * 32);
#pragma unroll
    for (int rI = 0; rI < 8; rI++) wfc[rI] = wp[rI];
  }
  bar_lds();

  // ---- stage 3b: pw3 via MFMA (K=64 as 2x K=32) + global max pool -> fcin(bufB) ----
  {
    const signed char* Ab = (const signed char*)bufAi;
    signed char* fcin = (signed char*)bufBi;
    int mx[2] = {-1000000, -1000000};
#pragma unroll
    for (int mt = 0; mt < 4; mt++) {
      int m = mt * 16 + lm;
      long a0 = *(const long*)(Ab + m * 72 + kg * 8);
      long a1 = *(const long*)(Ab + m * 72 + 32 + kg * 8);
#pragma unroll
      for (int h = 0; h < 2; h++) {
        v4i d = __builtin_amdgcn_mfma_i32_16x16x32_i8(a0, b0v[h],
                                                      (v4i){0, 0, 0, 0}, 0, 0, 0);
        d = __builtin_amdgcn_mfma_i32_16x16x32_i8(a1, b1v[h], d, 0, 0, 0);
        int t4 = max4(d);
        mx[h] = mx[h] > t4 ? mx[h] : t4;
      }
    }
#pragma unroll
    for (int h = 0; h < 2; h++) {
      int red = max(mx[h], __shfl_xor(mx[h], 16));
      red = max(red, __shfl_xor(red, 32));
      if (lane < 16)
        fcin[(wv * 2 + h) * 16 + lm] = (signed char)iclamp(rne4(red), 0, 7);
    }
  }
  bar_lds();

  // ---- fc1: 128 -> 256 (sdot4, prefetched weights) fcin(bufB) -> fc2in(bufA) ----
  {
    const int4* mp = (const int4*)bufBi;
    int acc = 0;
#pragma unroll
    for (int rI = 0; rI < 8; rI++) {
      int4 a = mp[rI]; int4 w = wfc[rI];
      acc = dot4(a.x, w.x, acc); acc = dot4(a.y, w.y, acc);
      acc = dot4(a.z, w.z, acc); acc = dot4(a.w, w.w, acc);
    }
    ((signed char*)bufAi)[tid] = (signed char)iclamp(rne4(acc), 0, 7);
  }
  bar_lds();

  // ---- fc2: 256 -> 10, single-wave shfl reduction ----
  if (tid < 40) {
    int k = tid >> 2, j = tid & 3;           // 4 lanes per class
    const int4* wp = (const int4*)(wq + WC2p + k * 64 + j * 16);
    const int4* ap = (const int4*)bufAi;
    int acc = 0;
#pragma unroll
    for (int r = 0; r < 4; r++) {
      int4 a = ap[j * 4 + r]; int4 w = wp[r];
      acc = dot4(a.x, w.x, acc); acc = dot4(a.y, w.y, acc);
      acc = dot4(a.z, w.z, acc); acc = dot4(a.w, w.w, acc);
    }
    acc += __shfl_xor(acc, 1);
    acc += __shfl_xor(acc, 2);
    if (j == 0) {
      // value = acc*0.125; fq_signed(v, 2^-4, 8b): round(v*16) = 2*acc exactly
      int code = iclamp(2 * acc, -128, 127);
      out[(size_t)img * 10 + k] = (float)code * 0.0625f;
    }
  }
}

extern "C" void kernel_launch(void* const* d_in, const int* in_sizes, int n_in,
                              void* d_out, int out_size, void* d_ws, size_t ws_size,
                              hipStream_t stream) {
  const float* x   = (const float*)d_in[0];
  const float* w0  = (const float*)d_in[1];
  const float* dw1 = (const float*)d_in[2];
  const float* pw1 = (const float*)d_in[3];
  const float* dw2 = (const float*)d_in[4];
  const float* pw2 = (const float*)d_in[5];
  const float* dw3 = (const float*)d_in[6];
  const float* pw3 = (const float*)d_in[7];
  const float* wc1 = (const float*)d_in[8];
  const float* wc2 = (const float*)d_in[9];
  int*   wsq = (int*)d_ws;     // 15380 ints = 61.5 KB (L2-resident)
  float* out = (float*)d_out;  // (1024,10,1,1) fp32

  prep_weights<<<(WTOT + 255) / 256, 256, 0, stream>>>(
      w0, dw1, pw1, dw2, pw2, dw3, pw3, wc1, wc2, wsq);
  fused_net<<<1024, 256, 0, stream>>>(x, wsq, out);
}